// Round 11
// baseline (35.455 us; speedup 1.0000x reference)
//
#include <hip/hip_runtime.h>
#include <math.h>

#define BB 2
#define LL 1024
#define SS 1024
#define HH 8
#define DD 64
#define PP 4
#define TL 16

typedef __attribute__((ext_vector_type(8))) short short8;
typedef __attribute__((ext_vector_type(4))) float floatx4;
typedef __attribute__((ext_vector_type(2))) float floatx2;

#if __has_builtin(__builtin_amdgcn_cosf)
#define COS2PI(x) __builtin_amdgcn_cosf(x)
#else
#define COS2PI(x) __cosf((x) * 6.283185307179586f)
#endif
#if __has_builtin(__builtin_amdgcn_exp2f)
#define EXP2F(x) __builtin_amdgcn_exp2f(x)
#else
#define EXP2F(x) exp2f(x)
#endif

// params pre-scaled by 1/(4*pi): q' = tanh(.)/4 so cos(2*pi*(q'-k')) = cos((qp-kp)/2)
__device__ __forceinline__ float scoreP(float4 q, float k0, float k1, float k2, float k3) {
    float c0 = COS2PI(q.x - k0);
    float c1 = COS2PI(q.y - k1);
    float c2 = COS2PI(q.z - k2);
    float c3 = COS2PI(q.w - k3);
    float prod = (c0 * c1) * (c2 * c3);
    return EXP2F(prod * 0.18033688011112042f); // exp(prod/8) ; log2(e)/8
}

// RNE pack of two f32 -> u32 (lo = a, hi = b), single HW instr
__device__ __forceinline__ unsigned cvt_pk_bf16(float a, float b) {
    unsigned r;
    asm("v_cvt_pk_bf16_f32 %0, %1, %2" : "=v"(r) : "v"(a), "v"(b));
    return r;
}
__device__ __forceinline__ float bf2f(unsigned u) { return __uint_as_float(u << 16); }

// ---------------- Kernel 1: prep ----------------
// blocks 0..255:   q-param tiles (64 rows each)
// blocks 256..511: k-param tiles
// blocks 512..767: V transpose -> bf16 [B,H,D,S]
__global__ __launch_bounds__(256) void qka_prep_kernel(
    const float* __restrict__ Q, const float* __restrict__ K, const float* __restrict__ V,
    const float* __restrict__ Wq, const float* __restrict__ bq,
    const float* __restrict__ Wk, const float* __restrict__ bk,
    float* __restrict__ qp_ws, float* __restrict__ kp_ws, unsigned short* __restrict__ vt_ws)
{
    __shared__ float sm[4480];          // params: [64*65] tile + [256] W ; transpose: [64*66]
    const int bid = blockIdx.x;
    const int t = threadIdx.x;

    if (bid < 512) {
        // ---- params: 64 rows per block; thread = (row = t&63, p = t>>6) ----
        const bool is_q = (bid < 256);
        const int r_base = (is_q ? bid : bid - 256) * 64;
        const float* in   = is_q ? Q  : K;
        const float* W    = is_q ? Wq : Wk;
        const float* bias = is_q ? bq : bk;

        float* tile = sm;               // [64][65]
        float* Wl   = sm + 64 * 65;     // [256]

        #pragma unroll
        for (int i = 0; i < 4; ++i) {
            int n = i * 256 + t;        // float4 index
            int row = n >> 4, dq = n & 15;
            float4 v = *reinterpret_cast<const float4*>(in + ((size_t)(r_base + row)) * DD + dq * 4);
            tile[row * 65 + dq * 4 + 0] = v.x;
            tile[row * 65 + dq * 4 + 1] = v.y;
            tile[row * 65 + dq * 4 + 2] = v.z;
            tile[row * 65 + dq * 4 + 3] = v.w;
        }
        Wl[t] = W[t];                   // 256 = DD*PP exactly
        __syncthreads();

        const int row = t & 63;
        const int p   = t >> 6;         // wave-uniform
        float acc = 0.f;
        #pragma unroll 16
        for (int d = 0; d < DD; ++d)
            acc += tile[row * 65 + d] * Wl[d * PP + p];

        const int r = r_base + row;     // r = (b*L + l)*H + h
        const int b   = r >> 13;
        const int l   = (r & 8191) >> 3;
        const int h   = r & 7;
        float v = 0.25f * tanhf(acc + bias[p]);
        float* outp = is_q ? qp_ws : kp_ws;
        outp[(((size_t)(b * HH + h)) * LL + l) * PP + p] = v;
    } else {
        // ---- V transpose tile: (b,h, s-tile of 64) -> vt_ws[b][h][d][s] bf16 ----
        const int tile_i = bid - 512;       // 0..255
        const int b  = tile_i >> 7;
        const int h  = (tile_i >> 4) & 7;
        const int s0 = (tile_i & 15) * 64;
        const int bh = b * HH + h;
        float* vt = sm;                      // [64][66]

        #pragma unroll
        for (int i = 0; i < 4; ++i) {
            int n = i * 256 + t;
            int s = n >> 4, dq = n & 15;
            float4 v = *reinterpret_cast<const float4*>(
                V + (((size_t)(b * SS + s0 + s)) * HH + h) * DD + dq * 4);
            vt[(dq * 4 + 0) * 66 + s] = v.x;
            vt[(dq * 4 + 1) * 66 + s] = v.y;
            vt[(dq * 4 + 2) * 66 + s] = v.z;
            vt[(dq * 4 + 3) * 66 + s] = v.w;
        }
        __syncthreads();
        unsigned* outp = reinterpret_cast<unsigned*>(vt_ws);
        #pragma unroll
        for (int rr = 0; rr < 8; ++rr) {
            int idx = rr * 256 + t;          // 0..2047
            int d = idx >> 5, sp = idx & 31;
            unsigned pk = cvt_pk_bf16(vt[d * 66 + 2 * sp], vt[d * 66 + 2 * sp + 1]);
            outp[((size_t)bh * DD + d) * (SS / 2) + (s0 >> 1) + sp] = pk;
        }
    }
}

// ---------------- Kernel 2: scores + softmax + attn write + MFMA PV ----------------
// grid 1024 = (b,h,lt), 256 thr, static LDS 40960B
// VERIFIED-PASSING BODY (R5, 35.5us). Four single-variable perturbations of this
// body (kp-stage removal, lane*4 chunking, store-split, launch_bounds 5) each
// produced deterministic ctx corruption with distinct absmax signatures that
// static analysis could not explain. Treat this body as schedule-sensitive:
// do not modify the score/store/PV region without a dedicated experiment.
__global__ __launch_bounds__(256, 4) void qka_main_kernel(
    const float* __restrict__ qp_ws,          // [B,H,L,P] fp32
    const float* __restrict__ kp_ws,          // [B,H,S,P] fp32
    const unsigned short* __restrict__ vt_ws, // [B,H,D,S] bf16
    float* __restrict__ out_ctx,              // [B,L,H,D]
    float* __restrict__ out_attn)             // [B,H,L,S]
{
    __shared__ unsigned short kp[SS * PP];    // 8192 B, bf16 params
    __shared__ unsigned short Pm[TL * SS];    // 32768 B, normalized bf16 w (XOR-swizzled)

    const int t   = threadIdx.x;
    const int bid = blockIdx.x;
    const int lt  = bid & 63;
    const int h   = (bid >> 6) & 7;
    const int b   = bid >> 9;
    const int bh  = b * HH + h;

    // ---- stage kp as bf16 ----
    const float4* kps = reinterpret_cast<const float4*>(kp_ws + (size_t)bh * SS * PP);
    #pragma unroll
    for (int r = 0; r < 4; ++r) {
        int s = r * 256 + t;
        float4 kv = kps[s];
        uint2 pk;
        pk.x = cvt_pk_bf16(kv.x, kv.y);
        pk.y = cvt_pk_bf16(kv.z, kv.w);
        *reinterpret_cast<uint2*>(&kp[s * 4]) = pk;
    }
    __syncthreads();

    const int wv = t >> 6, lane = t & 63;
    const int r0 = wv * 4;                    // this wave owns rows r0..r0+3

    float4 q4[4];
    #pragma unroll
    for (int i = 0; i < 4; ++i)
        q4[i] = *reinterpret_cast<const float4*>(
            qp_ws + ((size_t)bh * LL + lt * TL + r0 + i) * PP);

    // ---- pass A: P = exp(score) kept in REGISTERS (packed bf16), Z in regs ----
    unsigned pk[4][8];
    float zacc[4] = {0.f, 0.f, 0.f, 0.f};
    #pragma unroll
    for (int c = 0; c < 8; ++c) {
        int s = c * 128 + lane * 2;
        uint4 kk = *reinterpret_cast<const uint4*>(&kp[s * 4]);  // params of s, s+1
        float ka0 = bf2f(kk.x & 0xffffu), ka1 = bf2f(kk.x >> 16);
        float ka2 = bf2f(kk.y & 0xffffu), ka3 = bf2f(kk.y >> 16);
        float kb0 = bf2f(kk.z & 0xffffu), kb1 = bf2f(kk.z >> 16);
        float kb2 = bf2f(kk.w & 0xffffu), kb3 = bf2f(kk.w >> 16);
        #pragma unroll
        for (int i = 0; i < 4; ++i) {
            float e0 = scoreP(q4[i], ka0, ka1, ka2, ka3);
            float e1 = scoreP(q4[i], kb0, kb1, kb2, kb3);
            zacc[i] += e0 + e1;
            pk[i][c] = cvt_pk_bf16(e0, e1);
        }
    }

    // ---- Z reduce (wave-private rows, no barrier) ----
    #pragma unroll
    for (int i = 0; i < 4; ++i) {
        float z = zacc[i];
        #pragma unroll
        for (int off = 1; off < 64; off <<= 1) z += __shfl_xor(z, off);
        zacc[i] = 1.0f / z;
    }

    // ---- store pass: normalize from regs, nt-store attn fp32, write bf16 w -> Pm ----
    #pragma unroll
    for (int i = 0; i < 4; ++i) {
        int row = r0 + i;
        float rz = zacc[i];
        unsigned sw = (row & 7) << 4;
        float* abase = out_attn + ((size_t)bh * LL + lt * TL + row) * SS + lane * 2;
        #pragma unroll
        for (int c = 0; c < 8; ++c) {
            unsigned p = pk[i][c];
            float w0 = bf2f(p & 0xffffu) * rz;
            float w1 = bf2f(p >> 16) * rz;
            floatx2 wv2 = {w0, w1};
            __builtin_nontemporal_store(wv2, reinterpret_cast<floatx2*>(abase + c * 128));
            unsigned byte = (unsigned)(row * 2048 + c * 256 + lane * 4) ^ sw;
            *reinterpret_cast<unsigned*>(reinterpret_cast<char*>(Pm) + byte) = cvt_pk_bf16(w0, w1);
        }
    }
    __syncthreads();   // all rows' w visible to all waves

    // ---- PV: ctx[16 l][64 d] via mfma 16x16x32 bf16; wave wv -> d0 = wv*16 ----
    const int d0 = wv * 16;
    const int fr = lane & 15;     // A row (l), B col (d)
    const int hi = lane >> 4;     // k-group
    floatx4 acc = {0.f, 0.f, 0.f, 0.f};
    const unsigned short* vtb = vt_ws + ((size_t)bh * DD + d0 + fr) * SS + hi * 8;
    const unsigned swf = (unsigned)((fr & 7) << 4);
    #pragma unroll 4
    for (int st = 0; st < 32; ++st) {
        unsigned abyte = (unsigned)(fr * 2048 + st * 64 + hi * 16) ^ swf;
        short8 afrag = *reinterpret_cast<const short8*>(
            reinterpret_cast<char*>(Pm) + abyte);
        short8 bfrag = *reinterpret_cast<const short8*>(vtb + st * 32);
        acc = __builtin_amdgcn_mfma_f32_16x16x32_bf16(afrag, bfrag, acc, 0, 0, 0);
    }
    // D: row m = hi*4 + r, col n = fr
    #pragma unroll
    for (int r = 0; r < 4; ++r) {
        int l = lt * TL + hi * 4 + r;
        __builtin_nontemporal_store(acc[r],
            out_ctx + (((size_t)b * LL + l) * HH + h) * DD + d0 + fr);
    }
}

extern "C" void kernel_launch(void* const* d_in, const int* in_sizes, int n_in,
                              void* d_out, int out_size, void* d_ws, size_t ws_size,
                              hipStream_t stream) {
    const float* Q  = (const float*)d_in[0];
    const float* K  = (const float*)d_in[1];
    const float* V  = (const float*)d_in[2];
    const float* Wq = (const float*)d_in[3];
    const float* bq = (const float*)d_in[4];
    const float* Wk = (const float*)d_in[5];
    const float* bk = (const float*)d_in[6];

    float* out_ctx  = (float*)d_out;                           // [B,L,H,D]
    float* out_attn = out_ctx + (size_t)BB * LL * HH * DD;     // [B,H,L,S]

    float* qp_ws = (float*)d_ws;                               // 256 KB
    float* kp_ws = qp_ws + (size_t)BB * HH * LL * PP;          // 256 KB
    unsigned short* vt_ws = (unsigned short*)(kp_ws + (size_t)BB * HH * SS * PP); // 2 MB bf16 V^T

    // K1: params (512 blocks) + V transpose (256 blocks)
    qka_prep_kernel<<<768, 256, 0, stream>>>(Q, K, V, Wq, bq, Wk, bk, qp_ws, kp_ws, vt_ws);

    // K2: fused scores/softmax/attn/PV
    qka_main_kernel<<<BB * HH * (LL / TL), 256, 0, stream>>>(
        qp_ws, kp_ws, vt_ws, out_ctx, out_attn);
}